// Round 9
// baseline (137.353 us; speedup 1.0000x reference)
//
#include <hip/hip_runtime.h>
#include <math.h>

#define NN 8192
#define DD 128
#define NPAN 32                  // 256-row/col panels
#define NT 4                     // 4 col-tiles of 64 per block
#define NBLK (NPAN * (NPAN + 1) / 2)   // 528 triangle blocks
#define SQKE 3.7982825f          // sqrt(10*log2(e)); xn pre-scaled -> MFMA emits exp2-ready logits
#define LN2 0.6931471805599453f
#define NCLS 33

typedef __attribute__((ext_vector_type(8))) short short8;
typedef __attribute__((ext_vector_type(4))) float f32x4;

__device__ __forceinline__ unsigned short f2bf(float f) {
    unsigned u = __builtin_bit_cast(unsigned, f);
    unsigned r = (u + 0x7FFFu + ((u >> 16) & 1u)) >> 16;
    return (unsigned short)r;
}
__device__ __forceinline__ float bf2f(unsigned short h) {
    unsigned u = ((unsigned)h) << 16;
    return __builtin_bit_cast(float, u);
}
__device__ __forceinline__ int offp(int p) { return 32 * p - (p * (p - 1)) / 2; }

// ---- kernel 1: normalize+scale rows -> bf16, selfdot; zero Z/S/psum/pcnt ----
__global__ __launch_bounds__(256) void prep_kernel(const float* __restrict__ x,
                                                   unsigned short* __restrict__ xn,
                                                   float* __restrict__ sd,
                                                   float* __restrict__ zs) {
    const int b = blockIdx.x, t = threadIdx.x;
    const int zi = b * 256 + t;
    if (zi < 2 * NN + 64) zs[zi] = 0.f;          // Z[NN] S[NN] psum[32] pcnt[32]

    int row  = (b << 2) + (t >> 6);
    int lane = t & 63;
    float2 v = ((const float2*)(x + (size_t)row * DD))[lane];
    float ss = v.x * v.x + v.y * v.y;
    #pragma unroll
    for (int off = 32; off; off >>= 1) ss += __shfl_xor(ss, off);
    float rs = rsqrtf(ss) * SQKE;
    unsigned short bx = f2bf(v.x * rs), by = f2bf(v.y * rs);
    ushort2 st; st.x = bx; st.y = by;
    ((ushort2*)(xn + (size_t)row * DD))[lane] = st;
    float fx = bf2f(bx), fy = bf2f(by);
    float s2 = fx * fx + fy * fy;
    #pragma unroll
    for (int off = 32; off; off >>= 1) s2 += __shfl_xor(s2, off);
    if (lane == 0) sd[row] = s2;
}

// ---- kernel 2: MFMA similarity on the triangle; dual row/col emission ----
// 256 thr = 4 waves; wave owns 64 rows; block covers panel-pair (p,q), q>=p:
// rows [p*256,+256) x cols [q*256,+256). Off-diag blocks (q>p) emit BOTH
// row-sums and col-sums (d_ij = d_ji), halving total work. Diag blocks
// compute their full square (both orders present) and emit rows only.
__global__ __launch_bounds__(256) void cl_main(const unsigned short* __restrict__ xn,
                                               const int* __restrict__ labels,
                                               float* __restrict__ Z,
                                               float* __restrict__ S) {
    __shared__ __align__(16) unsigned short Bt[2][64][DD];   // 32 KB double buffer

    const int tid  = threadIdx.x;
    const int w    = tid >> 6;
    const int lane = tid & 63;
    const int l15  = lane & 15;
    const int lhi  = lane >> 4;

    // triangle decode: blockIdx -> (p,q), q >= p
    const int e = (int)blockIdx.x;
    int p = (int)((65.0f - sqrtf(4225.0f - 8.0f * (float)e)) * 0.5f);
    while (p > 0 && offp(p) > e) --p;
    while (offp(p + 1) <= e) ++p;
    const int q = p + (e - offp(p));
    const bool emitCol = (q > p);

    const int row0  = p * 256 + w * 64;
    const int jbase = q * 256;

    // A frags: lane holds A[row0 + mi*16 + l15][ks*32 + lhi*8 .. +7]
    short8 a[4][4];
    #pragma unroll
    for (int mi = 0; mi < 4; ++mi)
        #pragma unroll
        for (int ks = 0; ks < 4; ++ks)
            a[mi][ks] = *(const short8*)(xn + (size_t)(row0 + mi * 16 + l15) * DD + ks * 32 + lhi * 8);

    int labI[4][4];
    #pragma unroll
    for (int mi = 0; mi < 4; ++mi)
        #pragma unroll
        for (int r = 0; r < 4; ++r)
            labI[mi][r] = labels[row0 + mi * 16 + lhi * 4 + r];

    // staging: thread t stages row srow = t>>2, 16B-blocks {c4+4k}, swizzled
    // source (blk ^ (srow&7)) with linear LDS dest (involution; read applies same XOR)
    const int srow = tid >> 2, c4 = tid & 3;
    const unsigned short* sgr = xn + (size_t)(jbase + srow) * DD;

    float z[4][4], s[4][4];
    #pragma unroll
    for (int mi = 0; mi < 4; ++mi)
        #pragma unroll
        for (int r = 0; r < 4; ++r) { z[mi][r] = 0.f; s[mi][r] = 0.f; }
    float zc[NT][4], sc[NT][4];
    #pragma unroll
    for (int t8 = 0; t8 < NT; ++t8)
        #pragma unroll
        for (int ni = 0; ni < 4; ++ni) { zc[t8][ni] = 0.f; sc[t8][ni] = 0.f; }

    // prologue: stage tile 0
    #pragma unroll
    for (int k = 0; k < 4; ++k) {
        int blk = c4 + 4 * k;
        short8 v = *(const short8*)(sgr + (size_t)(blk ^ (srow & 7)) * 8);
        *(short8*)&Bt[0][srow][blk * 8] = v;
    }
    __syncthreads();

    const int sw = l15 & 7;
    #pragma unroll
    for (int t8 = 0; t8 < NT; ++t8) {
        const int cur = t8 & 1;
        const int j0 = jbase + t8 * 64;

        // phase A: issue next tile's global loads (latency hides under compute)
        short8 nx[4];
        if (t8 < NT - 1) {
            const unsigned short* sgn = sgr + (size_t)(t8 + 1) * 64 * DD;
            #pragma unroll
            for (int k = 0; k < 4; ++k)
                nx[k] = *(const short8*)(sgn + (size_t)((c4 + 4 * k) ^ (srow & 7)) * 8);
        }
        int lj[4];
        #pragma unroll
        for (int ni = 0; ni < 4; ++ni) lj[ni] = labels[j0 + ni * 16 + l15];

        // phase B: compute from Bt[cur]
        const char* rbase = (const char*)&Bt[cur][0][0] + l15 * 256;
        f32x4 acc[4][4];
        #pragma unroll
        for (int mi = 0; mi < 4; ++mi)
            #pragma unroll
            for (int ni = 0; ni < 4; ++ni) acc[mi][ni] = (f32x4){0.f, 0.f, 0.f, 0.f};

        #pragma unroll
        for (int ni = 0; ni < 4; ++ni) {
            short8 bfv[4];
            #pragma unroll
            for (int ks = 0; ks < 4; ++ks)
                bfv[ks] = *(const short8*)(rbase + ni * 4096 + ((((ks << 2) | lhi) ^ sw) << 4));
            #pragma unroll
            for (int ks = 0; ks < 4; ++ks)
                #pragma unroll
                for (int mi = 0; mi < 4; ++mi)
                    acc[mi][ni] = __builtin_amdgcn_mfma_f32_16x16x32_bf16(a[mi][ks], bfv[ks], acc[mi][ni], 0, 0, 0);
        }

        // epilogue: rows always; cols accumulated too (flushed only if emitCol)
        #pragma unroll
        for (int mi = 0; mi < 4; ++mi)
            #pragma unroll
            for (int ni = 0; ni < 4; ++ni)
                #pragma unroll
                for (int r = 0; r < 4; ++r) {
                    float d = acc[mi][ni][r];
                    float ex = __builtin_amdgcn_exp2f(d);
                    bool m = (lj[ni] == labI[mi][r]);
                    z[mi][r] += ex;
                    s[mi][r] += m ? d : 0.f;
                    zc[t8][ni] += ex;
                    sc[t8][ni] += m ? d : 0.f;
                }

        // phase C: write staged data into the other buffer
        if (t8 < NT - 1) {
            #pragma unroll
            for (int k = 0; k < 4; ++k)
                *(short8*)&Bt[cur ^ 1][srow][(c4 + 4 * k) * 8] = nx[k];
        }
        __syncthreads();
    }

    // row flush: reduce across the 16 col-lanes per row; atomicAdd into Z/S
    #pragma unroll
    for (int mi = 0; mi < 4; ++mi)
        #pragma unroll
        for (int r = 0; r < 4; ++r) {
            float zz = z[mi][r], ss = s[mi][r];
            #pragma unroll
            for (int off = 1; off < 16; off <<= 1) {
                zz += __shfl_xor(zz, off);
                ss += __shfl_xor(ss, off);
            }
            if (l15 == 0) {
                int row = row0 + mi * 16 + lhi * 4 + r;
                atomicAdd(&Z[row], zz);
                atomicAdd(&S[row], ss);
            }
        }

    // col flush (off-diagonal blocks only): reduce across the 4 lhi row-groups
    if (emitCol) {
        #pragma unroll
        for (int t8 = 0; t8 < NT; ++t8)
            #pragma unroll
            for (int ni = 0; ni < 4; ++ni) {
                float zz = zc[t8][ni], ss = sc[t8][ni];
                zz += __shfl_xor(zz, 16); zz += __shfl_xor(zz, 32);
                ss += __shfl_xor(ss, 16); ss += __shfl_xor(ss, 32);
                if (lhi == 0) {
                    int col = jbase + t8 * 64 + ni * 16 + l15;
                    atomicAdd(&Z[col], zz);
                    atomicAdd(&S[col], ss);
                }
            }
    }
}

// ---- kernel 3: per-row finalize + per-block partial loss ----
__global__ __launch_bounds__(256) void fin1(const float* __restrict__ Z,
                                            const float* __restrict__ S,
                                            const float* __restrict__ sd,
                                            const int* __restrict__ labels,
                                            float* __restrict__ psum,
                                            float* __restrict__ pcnt) {
    __shared__ int cnt[NCLS];
    __shared__ float rs[4], rc[4];
    const int t = threadIdx.x;
    if (t < NCLS) cnt[t] = 0;
    __syncthreads();
    for (int i = t; i < NN; i += 256) atomicAdd(&cnt[labels[i]], 1);
    __syncthreads();

    const int row = blockIdx.x * 256 + t;
    float Zr = Z[row] - __builtin_amdgcn_exp2f(sd[row]);   // remove self from denominator
    float Sr = S[row] - sd[row];                           // remove self from positive-sum
    int C = cnt[labels[row]] - 1;
    float pr = 0.f, vl = 0.f;
    if (C > 0) { pr = LN2 * Sr / (float)C - logf(Zr); vl = 1.f; }
    #pragma unroll
    for (int off = 32; off; off >>= 1) { pr += __shfl_xor(pr, off); vl += __shfl_xor(vl, off); }
    int wv = t >> 6, ln = t & 63;
    if (ln == 0) { rs[wv] = pr; rc[wv] = vl; }
    __syncthreads();
    if (t == 0) {
        psum[blockIdx.x] = rs[0] + rs[1] + rs[2] + rs[3];
        pcnt[blockIdx.x] = rc[0] + rc[1] + rc[2] + rc[3];
    }
}

__global__ void fin2(const float* __restrict__ psum, const float* __restrict__ pcnt,
                     float* __restrict__ out) {
    int t = threadIdx.x;
    float a = t < 32 ? psum[t] : 0.f;
    float c = t < 32 ? pcnt[t] : 0.f;
    #pragma unroll
    for (int off = 32; off; off >>= 1) { a += __shfl_xor(a, off); c += __shfl_xor(c, off); }
    if (t == 0) out[0] = -a / c;
}

extern "C" void kernel_launch(void* const* d_in, const int* in_sizes, int n_in,
                              void* d_out, int out_size, void* d_ws, size_t ws_size,
                              hipStream_t stream) {
    const float* x      = (const float*)d_in[0];
    const int*   labels = (const int*)d_in[1];
    float* out = (float*)d_out;
    char*  ws  = (char*)d_ws;

    size_t off = 0;
    unsigned short* xn = (unsigned short*)(ws + off); off += (size_t)NN * DD * 2;  // 2 MB
    float* sd = (float*)(ws + off); off += (size_t)NN * 4;                         // 32 KB
    float* zs = (float*)(ws + off); off += (size_t)(2 * NN + 64) * 4;              // 64.25 KB
    float* Z    = zs;
    float* S    = zs + NN;
    float* psum = zs + 2 * NN;
    float* pcnt = zs + 2 * NN + 32;

    prep_kernel<<<NN / 4, 256, 0, stream>>>(x, xn, sd, zs);
    cl_main<<<NBLK, 256, 0, stream>>>(xn, labels, Z, S);
    fin1<<<NN / 256, 256, 0, stream>>>(Z, S, sd, labels, psum, pcnt);
    fin2<<<1, 64, 0, stream>>>(psum, pcnt, out);
}

// Round 10
// 107.374 us; speedup vs baseline: 1.2792x; 1.2792x over previous
//
#include <hip/hip_runtime.h>
#include <math.h>

#define NN 8192
#define DD 128
#define NPAN 32                  // 256-row/col panels
#define NT 4                     // 4 col-tiles of 64 per block
#define NBLK (NPAN * (NPAN + 1) / 2)   // 528 triangle blocks
#define SQKE 3.7982825f          // sqrt(10*log2(e)); xn pre-scaled -> MFMA emits exp2-ready logits
#define LN2 0.6931471805599453f
#define NCLS 33

typedef __attribute__((ext_vector_type(8))) short short8;
typedef __attribute__((ext_vector_type(4))) float f32x4;

__device__ __forceinline__ unsigned short f2bf(float f) {
    unsigned u = __builtin_bit_cast(unsigned, f);
    unsigned r = (u + 0x7FFFu + ((u >> 16) & 1u)) >> 16;
    return (unsigned short)r;
}
__device__ __forceinline__ float bf2f(unsigned short h) {
    unsigned u = ((unsigned)h) << 16;
    return __builtin_bit_cast(float, u);
}
__device__ __forceinline__ int offp(int p) { return 32 * p - (p * (p - 1)) / 2; }

// ---- kernel 1: normalize+scale rows -> bf16, selfdot; zero Z/S/psum/pcnt ----
__global__ __launch_bounds__(256) void prep_kernel(const float* __restrict__ x,
                                                   unsigned short* __restrict__ xn,
                                                   float* __restrict__ sd,
                                                   float* __restrict__ zs) {
    const int b = blockIdx.x, t = threadIdx.x;
    const int zi = b * 256 + t;
    if (zi < 2 * NN + 64) zs[zi] = 0.f;          // Z[NN] S[NN] psum[32] pcnt[32]

    int row  = (b << 2) + (t >> 6);
    int lane = t & 63;
    float2 v = ((const float2*)(x + (size_t)row * DD))[lane];
    float ss = v.x * v.x + v.y * v.y;
    #pragma unroll
    for (int off = 32; off; off >>= 1) ss += __shfl_xor(ss, off);
    float rs = rsqrtf(ss) * SQKE;
    unsigned short bx = f2bf(v.x * rs), by = f2bf(v.y * rs);
    ushort2 st; st.x = bx; st.y = by;
    ((ushort2*)(xn + (size_t)row * DD))[lane] = st;
    float fx = bf2f(bx), fy = bf2f(by);
    float s2 = fx * fx + fy * fy;
    #pragma unroll
    for (int off = 32; off; off >>= 1) s2 += __shfl_xor(s2, off);
    if (lane == 0) sd[row] = s2;
}

// ---- kernel 2: MFMA similarity on the triangle; dual row/col emission ----
// 256 thr = 4 waves; wave owns 64 rows x 256 cols of panel-pair (p,q), q>=p.
// Off-diag blocks (q>p) also emit col-sums per tile (d_ij = d_ji): 51.6% of
// full-sweep work. Diag blocks compute their full square, rows only.
// Col partials flushed PER TILE (8 regs) -- do NOT hold [NT][4] accumulators
// across the loop: that pushed VGPR to 256 and spilled 45 MB/dispatch (R9).
__global__ __launch_bounds__(256) void cl_main(const unsigned short* __restrict__ xn,
                                               const int* __restrict__ labels,
                                               float* __restrict__ Z,
                                               float* __restrict__ S) {
    __shared__ __align__(16) unsigned short Bt[2][64][DD];   // 32 KB double buffer

    const int tid  = threadIdx.x;
    const int w    = tid >> 6;
    const int lane = tid & 63;
    const int l15  = lane & 15;
    const int lhi  = lane >> 4;

    // triangle decode: blockIdx -> (p,q), q >= p
    const int e = (int)blockIdx.x;
    int p = (int)((65.0f - sqrtf(4225.0f - 8.0f * (float)e)) * 0.5f);
    while (p > 0 && offp(p) > e) --p;
    while (offp(p + 1) <= e) ++p;
    const int q = p + (e - offp(p));
    const bool emitCol = (q > p);

    const int row0  = p * 256 + w * 64;
    const int jbase = q * 256;

    // A frags: lane holds A[row0 + mi*16 + l15][ks*32 + lhi*8 .. +7]
    short8 a[4][4];
    #pragma unroll
    for (int mi = 0; mi < 4; ++mi)
        #pragma unroll
        for (int ks = 0; ks < 4; ++ks)
            a[mi][ks] = *(const short8*)(xn + (size_t)(row0 + mi * 16 + l15) * DD + ks * 32 + lhi * 8);

    int labI[4][4];
    #pragma unroll
    for (int mi = 0; mi < 4; ++mi)
        #pragma unroll
        for (int r = 0; r < 4; ++r)
            labI[mi][r] = labels[row0 + mi * 16 + lhi * 4 + r];

    // staging (round-6 proven layout): wave w stages rows w*16 + 4*j + r4,
    // j=0..3; lane kk covers 16B block kk of the row. Swizzled global source
    // (blk ^ (row&7)), linear LDS dest; read applies the same XOR (involution).
    const int r4 = lane >> 4, kk = lane & 15;

    float z[4][4], s[4][4];
    #pragma unroll
    for (int mi = 0; mi < 4; ++mi)
        #pragma unroll
        for (int r = 0; r < 4; ++r) { z[mi][r] = 0.f; s[mi][r] = 0.f; }

    // prologue: stage tile 0
    #pragma unroll
    for (int j = 0; j < 4; ++j) {
        int srow = w * 16 + 4 * j + r4;
        short8 v = *(const short8*)(xn + (size_t)(jbase + srow) * DD + (size_t)(kk ^ (srow & 7)) * 8);
        *(short8*)&Bt[0][srow][kk * 8] = v;
    }
    __syncthreads();

    const int sw = l15 & 7;
    int cur = 0;
    for (int t8 = 0; t8 < NT; ++t8) {
        const int j0 = jbase + t8 * 64;

        // phase A: issue next tile's global loads (latency hides under compute)
        short8 nx[4];
        if (t8 < NT - 1) {
            const unsigned short* sgn = xn + (size_t)(jbase + (t8 + 1) * 64) * DD;
            #pragma unroll
            for (int j = 0; j < 4; ++j) {
                int srow = w * 16 + 4 * j + r4;
                nx[j] = *(const short8*)(sgn + (size_t)srow * DD + (size_t)(kk ^ (srow & 7)) * 8);
            }
        }
        int lj[4];
        #pragma unroll
        for (int ni = 0; ni < 4; ++ni) lj[ni] = labels[j0 + ni * 16 + l15];

        // phase B: compute from Bt[cur]
        const char* rbase = (const char*)&Bt[cur][0][0] + l15 * 256;
        f32x4 acc[4][4];
        #pragma unroll
        for (int mi = 0; mi < 4; ++mi)
            #pragma unroll
            for (int ni = 0; ni < 4; ++ni) acc[mi][ni] = (f32x4){0.f, 0.f, 0.f, 0.f};

        #pragma unroll
        for (int ni = 0; ni < 4; ++ni) {
            short8 bfv[4];
            #pragma unroll
            for (int ks = 0; ks < 4; ++ks)
                bfv[ks] = *(const short8*)(rbase + ni * 4096 + ((((ks << 2) | lhi) ^ sw) << 4));
            #pragma unroll
            for (int ks = 0; ks < 4; ++ks)
                #pragma unroll
                for (int mi = 0; mi < 4; ++mi)
                    acc[mi][ni] = __builtin_amdgcn_mfma_f32_16x16x32_bf16(a[mi][ks], bfv[ks], acc[mi][ni], 0, 0, 0);
        }

        // epilogue: row sums always; col sums per tile (flushed immediately)
        float zc[4] = {0.f, 0.f, 0.f, 0.f};
        float sc[4] = {0.f, 0.f, 0.f, 0.f};
        #pragma unroll
        for (int mi = 0; mi < 4; ++mi)
            #pragma unroll
            for (int ni = 0; ni < 4; ++ni)
                #pragma unroll
                for (int r = 0; r < 4; ++r) {
                    float d = acc[mi][ni][r];
                    float ex = __builtin_amdgcn_exp2f(d);
                    bool m = (lj[ni] == labI[mi][r]);
                    z[mi][r] += ex;
                    s[mi][r] += m ? d : 0.f;
                    zc[ni] += ex;
                    sc[ni] += m ? d : 0.f;
                }

        if (emitCol) {
            #pragma unroll
            for (int ni = 0; ni < 4; ++ni) {
                float zz = zc[ni], ss = sc[ni];
                zz += __shfl_xor(zz, 16); zz += __shfl_xor(zz, 32);
                ss += __shfl_xor(ss, 16); ss += __shfl_xor(ss, 32);
                if (lhi == 0) {
                    int col = j0 + ni * 16 + l15;
                    atomicAdd(&Z[col], zz);
                    atomicAdd(&S[col], ss);
                }
            }
        }

        // phase C: write staged data into the other buffer
        if (t8 < NT - 1) {
            #pragma unroll
            for (int j = 0; j < 4; ++j)
                *(short8*)&Bt[cur ^ 1][w * 16 + 4 * j + r4][kk * 8] = nx[j];
        }
        __syncthreads();
        cur ^= 1;
    }

    // row flush: reduce across the 16 col-lanes per row; atomicAdd into Z/S
    #pragma unroll
    for (int mi = 0; mi < 4; ++mi)
        #pragma unroll
        for (int r = 0; r < 4; ++r) {
            float zz = z[mi][r], ss = s[mi][r];
            #pragma unroll
            for (int off = 1; off < 16; off <<= 1) {
                zz += __shfl_xor(zz, off);
                ss += __shfl_xor(ss, off);
            }
            if (l15 == 0) {
                int row = row0 + mi * 16 + lhi * 4 + r;
                atomicAdd(&Z[row], zz);
                atomicAdd(&S[row], ss);
            }
        }
}

// ---- kernel 3: per-row finalize + per-block partial loss ----
__global__ __launch_bounds__(256) void fin1(const float* __restrict__ Z,
                                            const float* __restrict__ S,
                                            const float* __restrict__ sd,
                                            const int* __restrict__ labels,
                                            float* __restrict__ psum,
                                            float* __restrict__ pcnt) {
    __shared__ int cnt[NCLS];
    __shared__ float rs[4], rc[4];
    const int t = threadIdx.x;
    if (t < NCLS) cnt[t] = 0;
    __syncthreads();
    for (int i = t; i < NN; i += 256) atomicAdd(&cnt[labels[i]], 1);
    __syncthreads();

    const int row = blockIdx.x * 256 + t;
    float Zr = Z[row] - __builtin_amdgcn_exp2f(sd[row]);   // remove self from denominator
    float Sr = S[row] - sd[row];                           // remove self from positive-sum
    int C = cnt[labels[row]] - 1;
    float pr = 0.f, vl = 0.f;
    if (C > 0) { pr = LN2 * Sr / (float)C - logf(Zr); vl = 1.f; }
    #pragma unroll
    for (int off = 32; off; off >>= 1) { pr += __shfl_xor(pr, off); vl += __shfl_xor(vl, off); }
    int wv = t >> 6, ln = t & 63;
    if (ln == 0) { rs[wv] = pr; rc[wv] = vl; }
    __syncthreads();
    if (t == 0) {
        psum[blockIdx.x] = rs[0] + rs[1] + rs[2] + rs[3];
        pcnt[blockIdx.x] = rc[0] + rc[1] + rc[2] + rc[3];
    }
}

__global__ void fin2(const float* __restrict__ psum, const float* __restrict__ pcnt,
                     float* __restrict__ out) {
    int t = threadIdx.x;
    float a = t < 32 ? psum[t] : 0.f;
    float c = t < 32 ? pcnt[t] : 0.f;
    #pragma unroll
    for (int off = 32; off; off >>= 1) { a += __shfl_xor(a, off); c += __shfl_xor(c, off); }
    if (t == 0) out[0] = -a / c;
}

extern "C" void kernel_launch(void* const* d_in, const int* in_sizes, int n_in,
                              void* d_out, int out_size, void* d_ws, size_t ws_size,
                              hipStream_t stream) {
    const float* x      = (const float*)d_in[0];
    const int*   labels = (const int*)d_in[1];
    float* out = (float*)d_out;
    char*  ws  = (char*)d_ws;

    size_t off = 0;
    unsigned short* xn = (unsigned short*)(ws + off); off += (size_t)NN * DD * 2;  // 2 MB
    float* sd = (float*)(ws + off); off += (size_t)NN * 4;                         // 32 KB
    float* zs = (float*)(ws + off); off += (size_t)(2 * NN + 64) * 4;              // 64.25 KB
    float* Z    = zs;
    float* S    = zs + NN;
    float* psum = zs + 2 * NN;
    float* pcnt = zs + 2 * NN + 32;

    prep_kernel<<<NN / 4, 256, 0, stream>>>(x, xn, sd, zs);
    cl_main<<<NBLK, 256, 0, stream>>>(xn, labels, Z, S);
    fin1<<<NN / 256, 256, 0, stream>>>(Z, S, sd, labels, psum, pcnt);
    fin2<<<1, 64, 0, stream>>>(psum, pcnt, out);
}